// Round 8
// baseline (285.578 us; speedup 1.0000x reference)
//
#include <hip/hip_runtime.h>

// ---------------------------------------------------------------------------
// MultiheadAttention fwd, MI355X gfx950.
// B=2, S=2048, D=1024, H=16, DH=64.  Internal compute fp16 + fp32 MFMA acc.
// R11 (= R10 de-risked; R10 container-failed, audit clean, infra suspect):
//   - k_convert ELIMINATED: fp32->f16 conversion folded into the reg-staging
//     phase of k_qkv (embed/key/Wq/Wk/Wv) and k_proj (Wo). One fp32 HBM read
//     replaces read+write+re-read; GEMMs are latency-bound so the conversion
//     hides under the T14 dbuf pipeline.
//   - k_packmask RESTORED as separate launch (was merged in R10; de-risk).
//   - k_attn byte-identical to R8/R9 (72us, VALU54+MFMA34 ~= issue ceiling).
//   - 4 launches: packmask, qkv, attn, proj.
// ---------------------------------------------------------------------------

typedef _Float16 f16;
typedef __attribute__((ext_vector_type(8))) _Float16 f16x8;
typedef __attribute__((ext_vector_type(4))) _Float16 f16x4;
typedef __attribute__((ext_vector_type(4))) float f32x4;
typedef unsigned long long u64;
typedef unsigned int u32;

#define MFMA16 __builtin_amdgcn_mfma_f32_16x16x32_f16
#define MFMA16K16 __builtin_amdgcn_mfma_f32_16x16x16f16

__device__ __forceinline__ void gl16(const f16* g, f16* l) {
    __builtin_amdgcn_global_load_lds(
        (const __attribute__((address_space(1))) void*)(const void*)g,
        (__attribute__((address_space(3))) void*)(void*)l,
        16, 0, 0);
}

__device__ __forceinline__ f16x8 cvt8(float4 a, float4 b) {
    f16x8 o;
    o[0]=(f16)a.x; o[1]=(f16)a.y; o[2]=(f16)a.z; o[3]=(f16)a.w;
    o[4]=(f16)b.x; o[5]=(f16)b.y; o[6]=(f16)b.z; o[7]=(f16)b.w;
    return o;
}

// ---------------- kernel 1: pack attn_mask into bit words ------------------
__global__ __launch_bounds__(256) void k_packmask(
    const int* __restrict__ mask, u64* __restrict__ bits)
{
    int gw = (blockIdx.x * 256 + threadIdx.x) >> 6;   // row 0..4095
    int lane = threadIdx.x & 63;
    const int* row = mask + (long)gw * 2048;
    u64* out = bits + (long)gw * 32;
    #pragma unroll 4
    for (int c = 0; c < 32; ++c) {
        int v = row[c * 64 + lane];
        u64 b = __ballot(v != 0);
        if (lane == 0) out[c] = b;
    }
}

// ---------------- kernel 2: fused QKV GEMM (fp32 sources, cvt in staging) --
// T14 dbuf reg-staging, BK=32, XCD-swizzled grid (768 = 8*96).
__global__ __launch_bounds__(256) void k_qkv(
    const float* __restrict__ embed, const float* __restrict__ key,
    const float* __restrict__ wq, const float* __restrict__ wk, const float* __restrict__ wv,
    const float* __restrict__ bq, const float* __restrict__ bk, const float* __restrict__ bv,
    f16* __restrict__ Qh, f16* __restrict__ Kh, f16* __restrict__ Vt)
{
    int bid0 = blockIdx.x;
    int bid = (bid0 & 7) * 96 + (bid0 >> 3);      // XCD swizzle, 768 = 8*96
    int which = bid >> 8;
    int rr_ = bid & 255;
    int tm = rr_ >> 3, tn = rr_ & 7;
    const float* Xf = (which == 0) ? embed : key;
    const float* Wf = (which == 0) ? wq : (which == 1) ? wk : wv;
    const float* bias = (which == 0) ? bq : (which == 1) ? bk : bv;

    // 2 bufs x (la 4096 | lb 4096) = 16384 f16; Q/K bounce needs 17408 f16.
    __shared__ f16 smem[17408];

    int tid = threadIdx.x;
    int lane = tid & 63, wid = tid >> 6;
    int wr = wid >> 1, wc = wid & 1;
    int lm = lane & 15, qd = lane >> 4;

    f32x4 acc[4][4];
    #pragma unroll
    for (int i = 0; i < 4; i++)
        #pragma unroll
        for (int j = 0; j < 4; j++) acc[i][j] = (f32x4)0.0f;

    int m0 = tm * 128, n0 = tn * 128;

    // staging map: chunk ci = tid (+256) -> row = ci>>2 (and +64), cg = ci&3.
    // fp32 source: 2 float4 per 8-f16 chunk; convert at ds_write time.
    int row0 = tid >> 2, cg0 = tid & 3;
    int lw0 = row0 * 32 + (cg0 ^ (row0 & 3)) * 8;     // second chunk at +2048
    const float* gx0 = Xf + (long)(m0 + row0) * 1024 + cg0 * 8;
    const float* gx1 = gx0 + (long)64 * 1024;
    const float* gw0 = Wf + (long)(n0 + row0) * 1024 + cg0 * 8;
    const float* gw1 = gw0 + (long)64 * 1024;

    float4 xa0, xb0, xa1, xb1, wa0, wb0, wa1, wb1;

    #define QLOAD(k0)                                                          \
        xa0 = *(const float4*)&gx0[k0]; xb0 = *(const float4*)&gx0[(k0) + 4];  \
        xa1 = *(const float4*)&gx1[k0]; xb1 = *(const float4*)&gx1[(k0) + 4];  \
        wa0 = *(const float4*)&gw0[k0]; wb0 = *(const float4*)&gw0[(k0) + 4];  \
        wa1 = *(const float4*)&gw1[k0]; wb1 = *(const float4*)&gw1[(k0) + 4];

    #define QWRITE(d)                                                          \
        *(f16x8*)&(d)[lw0] = cvt8(xa0, xb0);                                   \
        *(f16x8*)&(d)[lw0 + 2048] = cvt8(xa1, xb1);                            \
        *(f16x8*)&(d)[4096 + lw0] = cvt8(wa0, wb0);                            \
        *(f16x8*)&(d)[4096 + lw0 + 2048] = cvt8(wa1, wb1);

    // prologue: tile 0 -> buf 0
    QLOAD(0);
    QWRITE(smem);

    for (int kt = 0; kt < 32; ++kt) {
        int pb = kt & 1;
        __syncthreads();                           // buf[pb] writes visible
        if (kt < 31) { QLOAD((kt + 1) * 32); }     // issue loads for kt+1
        const f16* la = smem + pb * 8192;
        const f16* lb = la + 4096;
        f16x8 af[4], bfr[4];
        #pragma unroll
        for (int i = 0; i < 4; i++) {
            int m = 64 * wr + 16 * i + lm;
            af[i] = *(const f16x8*)&la[m * 32 + (qd ^ (m & 3)) * 8];
            int n = 64 * wc + 16 * i + lm;
            bfr[i] = *(const f16x8*)&lb[n * 32 + (qd ^ (n & 3)) * 8];
        }
        __builtin_amdgcn_s_setprio(1);
        #pragma unroll
        for (int i = 0; i < 4; i++)
            #pragma unroll
            for (int j = 0; j < 4; j++)
                acc[i][j] = MFMA16(af[i], bfr[j], acc[i][j], 0, 0, 0);
        __builtin_amdgcn_s_setprio(0);
        __syncthreads();                           // reads of buf[pb] done
        if (kt < 31) {
            f16* d = smem + (pb ^ 1) * 8192;
            QWRITE(d);
        }
    }
    #undef QLOAD
    #undef QWRITE

    if (which == 2) {
        // V: direct transposed store [B][H][64][S], b64 along s
        #pragma unroll
        for (int j = 0; j < 4; j++) {
            int n = n0 + 64 * wc + 16 * j + lm;
            float bb = bias[n];
            int h = n >> 6, d = n & 63;
            #pragma unroll
            for (int i = 0; i < 4; i++) {
                int mbase = m0 + 64 * wr + 16 * i + 4 * qd;
                f16x4 pk;
                #pragma unroll
                for (int r = 0; r < 4; ++r) pk[r] = (f16)(acc[i][j][r] + bb);
                int b = mbase >> 11, s = mbase & 2047;
                *(f16x4*)&Vt[(((long)(b * 16 + h)) * 64 + d) * 2048 + s] = pk;
            }
        }
    } else {
        // Q/K: LDS bounce -> coalesced b128 row stores.
        // Q pre-scaled by (1/32)*log2(e). Loop's final sync precedes this.
        f16* dst = (which == 0) ? Qh : Kh;
        float sc = (which == 0) ? 0.0450842252f : 1.0f;
        #pragma unroll
        for (int j = 0; j < 4; j++) {
            int col = 64 * wc + 16 * j + lm;
            float bb = bias[n0 + col];
            #pragma unroll
            for (int i = 0; i < 4; i++) {
                int row = 64 * wr + 16 * i + 4 * qd;
                #pragma unroll
                for (int r = 0; r < 4; ++r)
                    smem[(row + r) * 136 + col] = (f16)((acc[i][j][r] + bb) * sc);
            }
        }
        __syncthreads();
        #pragma unroll
        for (int t = 0; t < 8; ++t) {
            int ci = tid + t * 256;            // 0..2047
            int row = ci >> 4, cg = ci & 15;
            f16x8 v = *(const f16x8*)&smem[row * 136 + cg * 8];
            int m = m0 + row;
            int b = m >> 11, s = m & 2047;
            int h = (n0 >> 6) + (cg >> 3);
            int d0 = (cg & 7) * 8;
            *(f16x8*)&dst[(((long)(b * 16 + h)) * 2048 + s) * 64 + d0] = v;
        }
    }
}

// ---------------- kernel 3: flash attention (2-phase dbuf, kv-split) -------
// 512 threads = 8 waves. Wave wid: q-slice (wid&3)*32, kv-half wid>>2.
// 64-key sub-tiles, double-buffered: STAGE(next) issued before compute(cur),
// one barrier per iter. Partial (O,l) combine via LDS (no-max softmax).
__global__ __launch_bounds__(512, 4) void k_attn(
    const f16* __restrict__ Qh, const f16* __restrict__ Kh, const f16* __restrict__ Vt,
    const u64* __restrict__ mbits, f16* __restrict__ O)
{
    int bid0 = blockIdx.x;
    int bid = (bid0 & 7) * 64 + (bid0 >> 3);      // XCD swizzle, 512 = 8*64
    int qt = bid & 15;
    int h = (bid >> 4) & 15;
    int b = bid >> 8;
    int q0 = qt * 128;

    const f16* Qg = Qh + ((long)(b * 16 + h)) * 2048 * 64;
    const f16* Kg = Kh + ((long)(b * 16 + h)) * 2048 * 64;
    const f16* Vg = Vt + ((long)(b * 16 + h)) * 64 * 2048;

    // 64 KB: 2 bufs x 16384 f16; buf: K0(4096) K1(4096) V0(4096) V1(4096)
    __shared__ f16 smem[32768];

    int tid = threadIdx.x, lane = tid & 63, wid = tid >> 6;   // wid 0..7
    int lm = lane & 15, qd = lane >> 4;
    int qs = wid & 3;          // q-slice 0..3
    int hf = wid >> 2;         // kv half 0/1

    int qb = q0 + 32 * qs;
    const u64* Mrow0 = mbits + ((long)(b * 2048) + qb + lm) * 32;
    const u64* Mrow1 = Mrow0 + 16 * 32;

    // ---- staging: wave stages bi = wid>>1 (0,1=K half; 2,3=V half),
    //      sub-half sub = wid&1; 4 gl16/wave/iter (4KB each).
    int bi = wid >> 1, sub = wid & 1;
    int rowL = lane >> 3;
    int cgL = (lane & 7) ^ rowL;
    const f16* gsrc; long lstep, istep; int doff;
    if (bi < 2) {              // K half bi: [64 key][64 d] swizzled
        gsrc = Kg + ((long)(bi * 1024 + sub * 32 + rowL)) * 64 + cgL * 8;
        lstep = 512;           // +8 key rows
        istep = 4096;          // +64 key rows per iter
        doff = bi * 4096 + sub * 2048;
    } else {                   // V half vh: V^T [64 d][64 key] swizzled
        int vh = bi - 2;
        gsrc = Vg + ((long)(sub * 32 + rowL)) * 2048 + vh * 1024 + cgL * 8;
        lstep = 16384;         // +8 d rows
        istep = 64;            // +64 keys per iter
        doff = 8192 + vh * 4096 + sub * 2048;
    }

    #define ATTN_STAGE(pb, it)                                                 \
        {                                                                      \
            f16* d0 = smem + (pb) * 16384 + doff;                              \
            const f16* s0_ = gsrc + (it) * istep;                              \
            _Pragma("unroll")                                                  \
            for (int li = 0; li < 4; ++li)                                     \
                gl16(s0_ + li * lstep, d0 + li * 512);                         \
        }

    // Q fragments (MFMA B operand), per group per 32-d half
    f16x8 aq[2][2];
    #pragma unroll
    for (int g = 0; g < 2; ++g)
        #pragma unroll
        for (int ksi = 0; ksi < 2; ++ksi)
            aq[g][ksi] = *(const f16x8*)&Qg[(long)(qb + 16 * g + lm) * 64 + ksi * 32 + qd * 8];

    f32x4 oacc[2][4], lacc[2];
    #pragma unroll
    for (int g = 0; g < 2; ++g) {
        #pragma unroll
        for (int c = 0; c < 4; c++) oacc[g][c] = (f32x4)0.0f;
        lacc[g] = (f32x4)0.0f;
    }
    f16x4 vone4;
    #pragma unroll
    for (int j = 0; j < 4; j++) vone4[j] = (f16)1.0f;

    float negc2 = -__builtin_amdgcn_exp2f(-0.5f * (float)(h + 1)) * 0.0450842252f;

    int vgq = qd >> 1;
    int off4 = (qd & 1) * 4;

    ATTN_STAGE(0, 0);
    __syncthreads();

    for (int it = 0; it < 16; ++it) {
        int pb = it & 1;
        if (it < 15) ATTN_STAGE(pb ^ 1, it + 1);

        const f16* ksH = smem + pb * 16384 + hf * 4096;
        const f16* vsH = smem + pb * 16384 + 8192 + hf * 4096;

        u64 wa = Mrow0[hf * 16 + it];
        u64 wb = Mrow1[hf * 16 + it];
        float qmk0 = (float)(qb + lm - hf * 1024 - it * 64 - 4 * qd);
        float qmk1 = qmk0 + 16.0f;

        #pragma unroll
        for (int c = 0; c < 4; ++c) {
            // S^T = K * Q^T for this 16-key chunk, both q-groups
            int kr = 16 * c + lm;
            f32x4 s0 = (f32x4)0.0f, s1 = (f32x4)0.0f;
            __builtin_amdgcn_s_setprio(1);
            #pragma unroll
            for (int ksi = 0; ksi < 2; ++ksi) {
                int gg = (ksi * 4 + qd) ^ (kr & 7);
                f16x8 ak = *(const f16x8*)&ksH[kr * 64 + gg * 8];
                s0 = MFMA16(ak, aq[0][ksi], s0, 0, 0, 0);
                s1 = MFMA16(ak, aq[1][ksi], s1, 0, 0, 0);
            }
            __builtin_amdgcn_s_setprio(0);
            // softmax (4 keys per lane at fixed q)
            u32 niba = (u32)(wa >> (16 * c + 4 * qd)) & 15u;
            u32 nibb = (u32)(wb >> (16 * c + 4 * qd)) & 15u;
            float qc0 = qmk0 - 16.0f * (float)c;
            float qc1 = qmk1 - 16.0f * (float)c;
            f16x4 pk0, pk1;
            #pragma unroll
            for (int r = 0; r < 4; ++r) {
                float u0 = fmaf(fabsf(qc0 - (float)r), negc2, s0[r]);
                u0 = ((niba >> r) & 1u) ? u0 : -1e30f;
                pk0[r] = (f16)__builtin_amdgcn_exp2f(u0);
                float u1 = fmaf(fabsf(qc1 - (float)r), negc2, s1[r]);
                u1 = ((nibb >> r) & 1u) ? u1 : -1e30f;
                pk1[r] = (f16)__builtin_amdgcn_exp2f(u1);
            }
            // O += P V : K=16 MFMA, A=pk (regs), B=V^T b64 from LDS
            int vgc = 2 * c + vgq;
            __builtin_amdgcn_s_setprio(1);
            #pragma unroll
            for (int cc = 0; cc < 4; ++cc) {
                int d = 16 * cc + lm;
                f16x4 vb = *(const f16x4*)&vsH[d * 64 + (vgc ^ (d & 7)) * 8 + off4];
                oacc[0][cc] = MFMA16K16(pk0, vb, oacc[0][cc], 0, 0, 0);
                oacc[1][cc] = MFMA16K16(pk1, vb, oacc[1][cc], 0, 0, 0);
            }
            lacc[0] = MFMA16K16(pk0, vone4, lacc[0], 0, 0, 0);
            lacc[1] = MFMA16K16(pk1, vone4, lacc[1], 0, 0, 0);
            __builtin_amdgcn_s_setprio(0);
        }
        __syncthreads();
    }
    #undef ATTN_STAGE

    // ---- combine epilogue: half 1 -> LDS, half 0 adds, normalize, bounce ---
    float* cO = (float*)smem;                     // [4][32][64] f32, 32 KB
    float* lL = (float*)(smem + 16384);           // [4][32] f32
    f16*  fO  = smem + 16640;                     // [4][32][64] f16, 16 KB

    if (hf == 1) {
        #pragma unroll
        for (int g = 0; g < 2; ++g) {
            #pragma unroll
            for (int cc = 0; cc < 4; ++cc)
                #pragma unroll
                for (int r = 0; r < 4; ++r)
                    cO[(qs * 32 + 16 * g + 4 * qd + r) * 64 + 16 * cc + lm] = oacc[g][cc][r];
            if (lm == 0) {
                #pragma unroll
                for (int r = 0; r < 4; ++r)
                    lL[qs * 32 + 16 * g + 4 * qd + r] = lacc[g][r];
            }
        }
    }
    __syncthreads();
    if (hf == 0) {
        #pragma unroll
        for (int g = 0; g < 2; ++g) {
            float linv[4];
            #pragma unroll
            for (int r = 0; r < 4; ++r)
                linv[r] = 1.0f / fmaxf(lacc[g][r] + lL[qs * 32 + 16 * g + 4 * qd + r], 1e-30f);
            #pragma unroll
            for (int cc = 0; cc < 4; ++cc)
                #pragma unroll
                for (int r = 0; r < 4; ++r) {
                    int idx = (qs * 32 + 16 * g + 4 * qd + r) * 64 + 16 * cc + lm;
                    fO[idx] = (f16)((oacc[g][cc][r] + cO[idx]) * linv[r]);
                }
        }
    }
    __syncthreads();
    // coalesced O store: 1024 chunks of 8 f16
    #pragma unroll
    for (int t = 0; t < 2; ++t) {
        int ci = tid + t * 512;                   // 0..1023
        int q = ci >> 3, dc = ci & 7;
        f16x8 v = *(const f16x8*)&fO[q * 64 + dc * 8];
        *(f16x8*)&O[((long)(b * 2048 + q0 + q)) * 1024 + h * 64 + dc * 8] = v;
    }
}

// ---------------- kernel 4: output projection (fp32 Wo converted in-stage) -
__global__ __launch_bounds__(256) void k_proj(
    const f16* __restrict__ Oh, const float* __restrict__ wo,
    const float* __restrict__ bo, float* __restrict__ out)
{
    int bid0 = blockIdx.x;
    int bid = (bid0 & 7) * 32 + (bid0 >> 3);      // XCD swizzle, 256 = 8*32
    int tm = bid >> 3, tn = bid & 7;

    __shared__ f16 smem[16384];   // 2 bufs x (la 4096 | lb 4096)

    int tid = threadIdx.x;
    int lane = tid & 63, wid = tid >> 6;
    int wr = wid >> 1, wc = wid & 1;
    int lm = lane & 15, qd = lane >> 4;

    f32x4 acc[4][4];
    #pragma unroll
    for (int i = 0; i < 4; i++)
        #pragma unroll
        for (int j = 0; j < 4; j++) acc[i][j] = (f32x4)0.0f;

    int m0 = tm * 128, n0 = tn * 128;

    int row0 = tid >> 2, cg0 = tid & 3;
    int lw0 = row0 * 32 + (cg0 ^ (row0 & 3)) * 8;     // second chunk at +2048
    const f16* gx0 = Oh + (long)(m0 + row0) * 1024 + cg0 * 8;
    const f16* gx1 = gx0 + (long)64 * 1024;
    const float* gw0 = wo + (long)(n0 + row0) * 1024 + cg0 * 8;
    const float* gw1 = gw0 + (long)64 * 1024;

    f16x8 rx0, rx1;
    float4 wa0, wb0, wa1, wb1;

    #define PLOAD(k0)                                                          \
        rx0 = *(const f16x8*)&gx0[k0];                                         \
        rx1 = *(const f16x8*)&gx1[k0];                                         \
        wa0 = *(const float4*)&gw0[k0]; wb0 = *(const float4*)&gw0[(k0) + 4];  \
        wa1 = *(const float4*)&gw1[k0]; wb1 = *(const float4*)&gw1[(k0) + 4];

    #define PWRITE(d)                                                          \
        *(f16x8*)&(d)[lw0] = rx0;                                              \
        *(f16x8*)&(d)[lw0 + 2048] = rx1;                                       \
        *(f16x8*)&(d)[4096 + lw0] = cvt8(wa0, wb0);                            \
        *(f16x8*)&(d)[4096 + lw0 + 2048] = cvt8(wa1, wb1);

    PLOAD(0);
    PWRITE(smem);

    for (int kt = 0; kt < 32; ++kt) {
        int pb = kt & 1;
        __syncthreads();
        if (kt < 31) { PLOAD((kt + 1) * 32); }
        const f16* la = smem + pb * 8192;
        const f16* lb = la + 4096;
        f16x8 af[4], bfr[4];
        #pragma unroll
        for (int i = 0; i < 4; i++) {
            int m = 64 * wr + 16 * i + lm;
            af[i] = *(const f16x8*)&la[m * 32 + (qd ^ (m & 3)) * 8];
            int n = 64 * wc + 16 * i + lm;
            bfr[i] = *(const f16x8*)&lb[n * 32 + (qd ^ (n & 3)) * 8];
        }
        __builtin_amdgcn_s_setprio(1);
        #pragma unroll
        for (int i = 0; i < 4; i++)
            #pragma unroll
            for (int j = 0; j < 4; j++)
                acc[i][j] = MFMA16(af[i], bfr[j], acc[i][j], 0, 0, 0);
        __builtin_amdgcn_s_setprio(0);
        __syncthreads();
        if (kt < 31) {
            f16* d = smem + (pb ^ 1) * 8192;
            PWRITE(d);
        }
    }
    #undef PLOAD
    #undef PWRITE

    #pragma unroll
    for (int j = 0; j < 4; j++) {
        int n = n0 + 64 * wc + 16 * j + lm;
        float bb = bo[n];
        #pragma unroll
        for (int i = 0; i < 4; i++) {
            int mbase = m0 + 64 * wr + 16 * i + 4 * qd;
            #pragma unroll
            for (int r = 0; r < 4; ++r)
                out[(long)(mbase + r) * 1024 + n] = acc[i][j][r] + bb;
        }
    }
}

// ---------------- launch ----------------------------------------------------
extern "C" void kernel_launch(void* const* d_in, const int* in_sizes, int n_in,
                              void* d_out, int out_size, void* d_ws, size_t ws_size,
                              hipStream_t stream)
{
    const float* embed = (const float*)d_in[0];
    const float* key   = (const float*)d_in[1];
    const int*   mask  = (const int*)d_in[2];
    const float* Wq = (const float*)d_in[3];
    const float* bq = (const float*)d_in[4];
    const float* Wk = (const float*)d_in[5];
    const float* bk = (const float*)d_in[6];
    const float* Wv = (const float*)d_in[7];
    const float* bv = (const float*)d_in[8];
    const float* Wo = (const float*)d_in[9];
    const float* bo = (const float*)d_in[10];

    char* ws = (char*)d_ws;
    f16* Qh  = (f16*)(ws + 0);          // 8 MB  [B][H][S][64]
    f16* Kh  = (f16*)(ws + 8388608);    // 8 MB
    f16* Vt  = (f16*)(ws + 16777216);   // 8 MB  [B][H][64][S]
    f16* Oh  = (f16*)(ws + 25165824);   // 8 MB  [B*S][1024]
    u64* mb  = (u64*)(ws + 33554432);   // 1 MB
    float* out = (float*)d_out;

    k_packmask<<<1024, 256, 0, stream>>>(mask, mb);
    k_qkv<<<768, 256, 0, stream>>>(embed, key, Wq, Wk, Wv, bq, bk, bv,
                                   Qh, Kh, Vt);
    k_attn<<<512, 512, 0, stream>>>(Qh, Kh, Vt, mb, Oh);
    k_proj<<<256, 256, 0, stream>>>(Oh, Wo, bo, out);
}

// Round 9
// 264.846 us; speedup vs baseline: 1.0783x; 1.0783x over previous
//
#include <hip/hip_runtime.h>

// ---------------------------------------------------------------------------
// MultiheadAttention fwd, MI355X gfx950.
// B=2, S=2048, D=1024, H=16, DH=64.  Internal compute fp16 + fp32 MFMA acc.
// R12 (= R9 best-known 263us + convert/packmask merged into one launch):
//   - R11's convert-in-GEMM-staging REVERTED (+22us: doubled staged bytes +
//     cvt VALU in the latency-critical path). Separate f16 convert restored.
//   - k_prep = k_convert (blocks 0..6143) + k_packmask (blocks 6144..7167):
//     both bodies barrier-free/LDS-free -> merge is strictly safe. 5->4
//     launches; mask blocks fill convert's tail.
//   - k_qkv/k_proj: R9 T14 dbuf reg-staged, BK=32, XCD swizzle (byte-equal).
//   - k_attn: R8/R9 2-phase gl16 dbuf kv-split (byte-equal; 70-72us stable).
// ---------------------------------------------------------------------------

typedef _Float16 f16;
typedef __attribute__((ext_vector_type(8))) _Float16 f16x8;
typedef __attribute__((ext_vector_type(4))) _Float16 f16x4;
typedef __attribute__((ext_vector_type(4))) float f32x4;
typedef unsigned long long u64;
typedef unsigned int u32;

#define MFMA16 __builtin_amdgcn_mfma_f32_16x16x32_f16
#define MFMA16K16 __builtin_amdgcn_mfma_f32_16x16x16f16

__device__ __forceinline__ void gl16(const f16* g, f16* l) {
    __builtin_amdgcn_global_load_lds(
        (const __attribute__((address_space(1))) void*)(const void*)g,
        (__attribute__((address_space(3))) void*)(void*)l,
        16, 0, 0);
}

// ---------------- kernel 1: convert + mask pack (merged, barrier-free) -----
__global__ __launch_bounds__(256) void k_prep(
    const float* __restrict__ embed, const float* __restrict__ key,
    const float* __restrict__ wq, const float* __restrict__ wk,
    const float* __restrict__ wv, const float* __restrict__ wo,
    const int* __restrict__ mask,
    f16* __restrict__ xe, f16* __restrict__ xk,
    f16* __restrict__ wqh, f16* __restrict__ wkh,
    f16* __restrict__ wvh, f16* __restrict__ woh,
    u64* __restrict__ bits)
{
    int bid = blockIdx.x;
    if (bid >= 6144) {
        // ---- mask packing: 1024 blocks, one mask row per wave ----
        int gw = ((bid - 6144) * 256 + (int)threadIdx.x) >> 6;   // 0..4095
        int lane = threadIdx.x & 63;
        const int* row = mask + (long)gw * 2048;
        u64* outp = bits + (long)gw * 32;
        #pragma unroll 4
        for (int c = 0; c < 32; ++c) {
            int v = row[c * 64 + lane];
            u64 b = __ballot(v != 0);
            if (lane == 0) outp[c] = b;
        }
        return;
    }
    // ---- fp32 -> f16 convert: one 8-float group per thread ----
    long g = (long)bid * 256 + threadIdx.x;
    const float* src; f16* dst; long off;
    if (g < 524288)       { src = embed; dst = xe; off = g; }
    else if (g < 1048576) { src = key;   dst = xk; off = g - 524288; }
    else {
        long t = g - 1048576; int wi = (int)(t >> 17); off = t & 131071;
        if (wi == 0)      { src = wq; dst = wqh; }
        else if (wi == 1) { src = wk; dst = wkh; }
        else if (wi == 2) { src = wv; dst = wvh; }
        else              { src = wo; dst = woh; }
    }
    const float4* s4 = (const float4*)src;
    float4 a = s4[off * 2], b = s4[off * 2 + 1];
    f16x8 o;
    o[0]=(f16)a.x; o[1]=(f16)a.y; o[2]=(f16)a.z; o[3]=(f16)a.w;
    o[4]=(f16)b.x; o[5]=(f16)b.y; o[6]=(f16)b.z; o[7]=(f16)b.w;
    *(f16x8*)(dst + off * 8) = o;
}

// ---------------- kernel 2: fused QKV GEMM (T14 dbuf reg-staged) -----------
// BK=32, 2x8KB LDS buffers. Per iter: sync / issue loads kt+1 / compute pb /
// sync / ds_write pb^1. XCD-swizzled grid (768 = 8*96).
__global__ __launch_bounds__(256) void k_qkv(
    const f16* __restrict__ xe, const f16* __restrict__ xk,
    const f16* __restrict__ wqh, const f16* __restrict__ wkh, const f16* __restrict__ wvh,
    const float* __restrict__ bq, const float* __restrict__ bk, const float* __restrict__ bv,
    f16* __restrict__ Qh, f16* __restrict__ Kh, f16* __restrict__ Vt)
{
    int bid0 = blockIdx.x;
    int bid = (bid0 & 7) * 96 + (bid0 >> 3);      // XCD swizzle, 768 = 8*96
    int which = bid >> 8;
    int rr_ = bid & 255;
    int tm = rr_ >> 3, tn = rr_ & 7;
    const f16* X = (which == 0) ? xe : xk;
    const f16* W = (which == 0) ? wqh : (which == 1) ? wkh : wvh;
    const float* bias = (which == 0) ? bq : (which == 1) ? bk : bv;

    // 2 bufs x (la 4096 | lb 4096) = 16384 f16; Q/K bounce needs 17408 f16.
    __shared__ f16 smem[17408];

    int tid = threadIdx.x;
    int lane = tid & 63, wid = tid >> 6;
    int wr = wid >> 1, wc = wid & 1;
    int lm = lane & 15, qd = lane >> 4;

    f32x4 acc[4][4];
    #pragma unroll
    for (int i = 0; i < 4; i++)
        #pragma unroll
        for (int j = 0; j < 4; j++) acc[i][j] = (f32x4)0.0f;

    int m0 = tm * 128, n0 = tn * 128;

    // staging map: chunk ci = tid + t*256 (t=0,1) -> row = ci>>2, cg = ci&3.
    // LDS slot sw = cg ^ (row&3) (XOR swizzle for conflict-free frag reads).
    int row0 = tid >> 2, cg0 = tid & 3;
    int row1 = (tid + 256) >> 2, cg1 = (tid + 256) & 3;
    int lw0 = row0 * 32 + (cg0 ^ (row0 & 3)) * 8;
    int lw1 = row1 * 32 + (cg1 ^ (row1 & 3)) * 8;
    const f16* gx0 = X + (long)(m0 + row0) * 1024 + cg0 * 8;
    const f16* gx1 = X + (long)(m0 + row1) * 1024 + cg1 * 8;
    const f16* gw0 = W + (long)(n0 + row0) * 1024 + cg0 * 8;
    const f16* gw1 = W + (long)(n0 + row1) * 1024 + cg1 * 8;

    f16x8 rx0, rx1, rw0, rw1;
    // prologue: load tile 0, write buf 0
    rx0 = *(const f16x8*)&gx0[0];
    rx1 = *(const f16x8*)&gx1[0];
    rw0 = *(const f16x8*)&gw0[0];
    rw1 = *(const f16x8*)&gw1[0];
    *(f16x8*)&smem[lw0] = rx0;
    *(f16x8*)&smem[lw1] = rx1;
    *(f16x8*)&smem[4096 + lw0] = rw0;
    *(f16x8*)&smem[4096 + lw1] = rw1;

    for (int kt = 0; kt < 32; ++kt) {
        int pb = kt & 1;
        __syncthreads();                           // buf[pb] writes visible
        if (kt < 31) {                             // issue loads for kt+1
            int k0 = (kt + 1) * 32;
            rx0 = *(const f16x8*)&gx0[k0];
            rx1 = *(const f16x8*)&gx1[k0];
            rw0 = *(const f16x8*)&gw0[k0];
            rw1 = *(const f16x8*)&gw1[k0];
        }
        const f16* la = smem + pb * 8192;
        const f16* lb = la + 4096;
        f16x8 af[4], bfr[4];
        #pragma unroll
        for (int i = 0; i < 4; i++) {
            int m = 64 * wr + 16 * i + lm;
            af[i] = *(const f16x8*)&la[m * 32 + (qd ^ (m & 3)) * 8];
            int n = 64 * wc + 16 * i + lm;
            bfr[i] = *(const f16x8*)&lb[n * 32 + (qd ^ (n & 3)) * 8];
        }
        __builtin_amdgcn_s_setprio(1);
        #pragma unroll
        for (int i = 0; i < 4; i++)
            #pragma unroll
            for (int j = 0; j < 4; j++)
                acc[i][j] = MFMA16(af[i], bfr[j], acc[i][j], 0, 0, 0);
        __builtin_amdgcn_s_setprio(0);
        __syncthreads();                           // reads of buf[pb] done
        if (kt < 31) {
            f16* d = smem + (pb ^ 1) * 8192;
            *(f16x8*)&d[lw0] = rx0;
            *(f16x8*)&d[lw1] = rx1;
            *(f16x8*)&d[4096 + lw0] = rw0;
            *(f16x8*)&d[4096 + lw1] = rw1;
        }
    }

    if (which == 2) {
        // V: direct transposed store [B][H][64][S], b64 along s
        #pragma unroll
        for (int j = 0; j < 4; j++) {
            int n = n0 + 64 * wc + 16 * j + lm;
            float bb = bias[n];
            int h = n >> 6, d = n & 63;
            #pragma unroll
            for (int i = 0; i < 4; i++) {
                int mbase = m0 + 64 * wr + 16 * i + 4 * qd;
                f16x4 pk;
                #pragma unroll
                for (int r = 0; r < 4; ++r) pk[r] = (f16)(acc[i][j][r] + bb);
                int b = mbase >> 11, s = mbase & 2047;
                *(f16x4*)&Vt[(((long)(b * 16 + h)) * 64 + d) * 2048 + s] = pk;
            }
        }
    } else {
        // Q/K: LDS bounce -> coalesced b128 row stores.
        // Q pre-scaled by (1/32)*log2(e). Loop's final sync precedes this.
        f16* dst = (which == 0) ? Qh : Kh;
        float sc = (which == 0) ? 0.0450842252f : 1.0f;
        #pragma unroll
        for (int j = 0; j < 4; j++) {
            int col = 64 * wc + 16 * j + lm;
            float bb = bias[n0 + col];
            #pragma unroll
            for (int i = 0; i < 4; i++) {
                int row = 64 * wr + 16 * i + 4 * qd;
                #pragma unroll
                for (int r = 0; r < 4; ++r)
                    smem[(row + r) * 136 + col] = (f16)((acc[i][j][r] + bb) * sc);
            }
        }
        __syncthreads();
        #pragma unroll
        for (int t = 0; t < 8; ++t) {
            int ci = tid + t * 256;            // 0..2047
            int row = ci >> 4, cg = ci & 15;
            f16x8 v = *(const f16x8*)&smem[row * 136 + cg * 8];
            int m = m0 + row;
            int b = m >> 11, s = m & 2047;
            int h = (n0 >> 6) + (cg >> 3);
            int d0 = (cg & 7) * 8;
            *(f16x8*)&dst[(((long)(b * 16 + h)) * 2048 + s) * 64 + d0] = v;
        }
    }
}

// ---------------- kernel 3: flash attention (2-phase dbuf, kv-split) -------
// 512 threads = 8 waves. Wave wid: q-slice (wid&3)*32, kv-half wid>>2.
// 64-key sub-tiles, double-buffered: STAGE(next) issued before compute(cur),
// one barrier per iter. Partial (O,l) combine via LDS (no-max softmax).
__global__ __launch_bounds__(512, 4) void k_attn(
    const f16* __restrict__ Qh, const f16* __restrict__ Kh, const f16* __restrict__ Vt,
    const u64* __restrict__ mbits, f16* __restrict__ O)
{
    int bid0 = blockIdx.x;
    int bid = (bid0 & 7) * 64 + (bid0 >> 3);      // XCD swizzle, 512 = 8*64
    int qt = bid & 15;
    int h = (bid >> 4) & 15;
    int b = bid >> 8;
    int q0 = qt * 128;

    const f16* Qg = Qh + ((long)(b * 16 + h)) * 2048 * 64;
    const f16* Kg = Kh + ((long)(b * 16 + h)) * 2048 * 64;
    const f16* Vg = Vt + ((long)(b * 16 + h)) * 64 * 2048;

    // 64 KB: 2 bufs x 16384 f16; buf: K0(4096) K1(4096) V0(4096) V1(4096)
    __shared__ f16 smem[32768];

    int tid = threadIdx.x, lane = tid & 63, wid = tid >> 6;   // wid 0..7
    int lm = lane & 15, qd = lane >> 4;
    int qs = wid & 3;          // q-slice 0..3
    int hf = wid >> 2;         // kv half 0/1

    int qb = q0 + 32 * qs;
    const u64* Mrow0 = mbits + ((long)(b * 2048) + qb + lm) * 32;
    const u64* Mrow1 = Mrow0 + 16 * 32;

    // ---- staging: wave stages bi = wid>>1 (0,1=K half; 2,3=V half),
    //      sub-half sub = wid&1; 4 gl16/wave/iter (4KB each).
    int bi = wid >> 1, sub = wid & 1;
    int rowL = lane >> 3;
    int cgL = (lane & 7) ^ rowL;
    const f16* gsrc; long lstep, istep; int doff;
    if (bi < 2) {              // K half bi: [64 key][64 d] swizzled
        gsrc = Kg + ((long)(bi * 1024 + sub * 32 + rowL)) * 64 + cgL * 8;
        lstep = 512;           // +8 key rows
        istep = 4096;          // +64 key rows per iter
        doff = bi * 4096 + sub * 2048;
    } else {                   // V half vh: V^T [64 d][64 key] swizzled
        int vh = bi - 2;
        gsrc = Vg + ((long)(sub * 32 + rowL)) * 2048 + vh * 1024 + cgL * 8;
        lstep = 16384;         // +8 d rows
        istep = 64;            // +64 keys per iter
        doff = 8192 + vh * 4096 + sub * 2048;
    }

    #define ATTN_STAGE(pb, it)                                                 \
        {                                                                      \
            f16* d0 = smem + (pb) * 16384 + doff;                              \
            const f16* s0_ = gsrc + (it) * istep;                              \
            _Pragma("unroll")                                                  \
            for (int li = 0; li < 4; ++li)                                     \
                gl16(s0_ + li * lstep, d0 + li * 512);                         \
        }

    // Q fragments (MFMA B operand), per group per 32-d half
    f16x8 aq[2][2];
    #pragma unroll
    for (int g = 0; g < 2; ++g)
        #pragma unroll
        for (int ksi = 0; ksi < 2; ++ksi)
            aq[g][ksi] = *(const f16x8*)&Qg[(long)(qb + 16 * g + lm) * 64 + ksi * 32 + qd * 8];

    f32x4 oacc[2][4], lacc[2];
    #pragma unroll
    for (int g = 0; g < 2; ++g) {
        #pragma unroll
        for (int c = 0; c < 4; c++) oacc[g][c] = (f32x4)0.0f;
        lacc[g] = (f32x4)0.0f;
    }
    f16x4 vone4;
    #pragma unroll
    for (int j = 0; j < 4; j++) vone4[j] = (f16)1.0f;

    float negc2 = -__builtin_amdgcn_exp2f(-0.5f * (float)(h + 1)) * 0.0450842252f;

    int vgq = qd >> 1;
    int off4 = (qd & 1) * 4;

    ATTN_STAGE(0, 0);
    __syncthreads();

    for (int it = 0; it < 16; ++it) {
        int pb = it & 1;
        if (it < 15) ATTN_STAGE(pb ^ 1, it + 1);

        const f16* ksH = smem + pb * 16384 + hf * 4096;
        const f16* vsH = smem + pb * 16384 + 8192 + hf * 4096;

        u64 wa = Mrow0[hf * 16 + it];
        u64 wb = Mrow1[hf * 16 + it];
        float qmk0 = (float)(qb + lm - hf * 1024 - it * 64 - 4 * qd);
        float qmk1 = qmk0 + 16.0f;

        #pragma unroll
        for (int c = 0; c < 4; ++c) {
            // S^T = K * Q^T for this 16-key chunk, both q-groups
            int kr = 16 * c + lm;
            f32x4 s0 = (f32x4)0.0f, s1 = (f32x4)0.0f;
            __builtin_amdgcn_s_setprio(1);
            #pragma unroll
            for (int ksi = 0; ksi < 2; ++ksi) {
                int gg = (ksi * 4 + qd) ^ (kr & 7);
                f16x8 ak = *(const f16x8*)&ksH[kr * 64 + gg * 8];
                s0 = MFMA16(ak, aq[0][ksi], s0, 0, 0, 0);
                s1 = MFMA16(ak, aq[1][ksi], s1, 0, 0, 0);
            }
            __builtin_amdgcn_s_setprio(0);
            // softmax (4 keys per lane at fixed q)
            u32 niba = (u32)(wa >> (16 * c + 4 * qd)) & 15u;
            u32 nibb = (u32)(wb >> (16 * c + 4 * qd)) & 15u;
            float qc0 = qmk0 - 16.0f * (float)c;
            float qc1 = qmk1 - 16.0f * (float)c;
            f16x4 pk0, pk1;
            #pragma unroll
            for (int r = 0; r < 4; ++r) {
                float u0 = fmaf(fabsf(qc0 - (float)r), negc2, s0[r]);
                u0 = ((niba >> r) & 1u) ? u0 : -1e30f;
                pk0[r] = (f16)__builtin_amdgcn_exp2f(u0);
                float u1 = fmaf(fabsf(qc1 - (float)r), negc2, s1[r]);
                u1 = ((nibb >> r) & 1u) ? u1 : -1e30f;
                pk1[r] = (f16)__builtin_amdgcn_exp2f(u1);
            }
            // O += P V : K=16 MFMA, A=pk (regs), B=V^T b64 from LDS
            int vgc = 2 * c + vgq;
            __builtin_amdgcn_s_setprio(1);
            #pragma unroll
            for (int cc = 0; cc < 4; ++cc) {
                int d = 16 * cc + lm;
                f16x4 vb = *(const f16x4*)&vsH[d * 64 + (vgc ^ (d & 7)) * 8 + off4];
                oacc[0][cc] = MFMA16K16(pk0, vb, oacc[0][cc], 0, 0, 0);
                oacc[1][cc] = MFMA16K16(pk1, vb, oacc[1][cc], 0, 0, 0);
            }
            lacc[0] = MFMA16K16(pk0, vone4, lacc[0], 0, 0, 0);
            lacc[1] = MFMA16K16(pk1, vone4, lacc[1], 0, 0, 0);
            __builtin_amdgcn_s_setprio(0);
        }
        __syncthreads();
    }
    #undef ATTN_STAGE

    // ---- combine epilogue: half 1 -> LDS, half 0 adds, normalize, bounce ---
    float* cO = (float*)smem;                     // [4][32][64] f32, 32 KB
    float* lL = (float*)(smem + 16384);           // [4][32] f32
    f16*  fO  = smem + 16640;                     // [4][32][64] f16, 16 KB

    if (hf == 1) {
        #pragma unroll
        for (int g = 0; g < 2; ++g) {
            #pragma unroll
            for (int cc = 0; cc < 4; ++cc)
                #pragma unroll
                for (int r = 0; r < 4; ++r)
                    cO[(qs * 32 + 16 * g + 4 * qd + r) * 64 + 16 * cc + lm] = oacc[g][cc][r];
            if (lm == 0) {
                #pragma unroll
                for (int r = 0; r < 4; ++r)
                    lL[qs * 32 + 16 * g + 4 * qd + r] = lacc[g][r];
            }
        }
    }
    __syncthreads();
    if (hf == 0) {
        #pragma unroll
        for (int g = 0; g < 2; ++g) {
            float linv[4];
            #pragma unroll
            for (int r = 0; r < 4; ++r)
                linv[r] = 1.0f / fmaxf(lacc[g][r] + lL[qs * 32 + 16 * g + 4 * qd + r], 1e-30f);
            #pragma unroll
            for (int cc = 0; cc < 4; ++cc)
                #pragma unroll
                for (int r = 0; r < 4; ++r) {
                    int idx = (qs * 32 + 16 * g + 4 * qd + r) * 64 + 16 * cc + lm;
                    fO[idx] = (f16)((oacc[g][cc][r] + cO[idx]) * linv[r]);
                }
        }
    }
    __syncthreads();
    // coalesced O store: 1024 chunks of 8 f16
    #pragma unroll
    for (int t = 0; t < 2; ++t) {
        int ci = tid + t * 512;                   // 0..1023
        int q = ci >> 3, dc = ci & 7;
        f16x8 v = *(const f16x8*)&fO[q * 64 + dc * 8];
        *(f16x8*)&O[((long)(b * 2048 + q0 + q)) * 1024 + h * 64 + dc * 8] = v;
    }
}

// ---------------- kernel 4: output projection (T14 dbuf reg-staged) --------
__global__ __launch_bounds__(256) void k_proj(
    const f16* __restrict__ Oh, const f16* __restrict__ woh,
    const float* __restrict__ bo, float* __restrict__ out)
{
    int bid0 = blockIdx.x;
    int bid = (bid0 & 7) * 32 + (bid0 >> 3);      // XCD swizzle, 256 = 8*32
    int tm = bid >> 3, tn = bid & 7;

    __shared__ f16 smem[16384];   // 2 bufs x (la 4096 | lb 4096)

    int tid = threadIdx.x;
    int lane = tid & 63, wid = tid >> 6;
    int wr = wid >> 1, wc = wid & 1;
    int lm = lane & 15, qd = lane >> 4;

    f32x4 acc[4][4];
    #pragma unroll
    for (int i = 0; i < 4; i++)
        #pragma unroll
        for (int j = 0; j < 4; j++) acc[i][j] = (f32x4)0.0f;

    int m0 = tm * 128, n0 = tn * 128;

    int row0 = tid >> 2, cg0 = tid & 3;
    int row1 = (tid + 256) >> 2, cg1 = (tid + 256) & 3;
    int lw0 = row0 * 32 + (cg0 ^ (row0 & 3)) * 8;
    int lw1 = row1 * 32 + (cg1 ^ (row1 & 3)) * 8;
    const f16* gx0 = Oh  + (long)(m0 + row0) * 1024 + cg0 * 8;
    const f16* gx1 = Oh  + (long)(m0 + row1) * 1024 + cg1 * 8;
    const f16* gw0 = woh + (long)(n0 + row0) * 1024 + cg0 * 8;
    const f16* gw1 = woh + (long)(n0 + row1) * 1024 + cg1 * 8;

    f16x8 rx0, rx1, rw0, rw1;
    rx0 = *(const f16x8*)&gx0[0];
    rx1 = *(const f16x8*)&gx1[0];
    rw0 = *(const f16x8*)&gw0[0];
    rw1 = *(const f16x8*)&gw1[0];
    *(f16x8*)&smem[lw0] = rx0;
    *(f16x8*)&smem[lw1] = rx1;
    *(f16x8*)&smem[4096 + lw0] = rw0;
    *(f16x8*)&smem[4096 + lw1] = rw1;

    for (int kt = 0; kt < 32; ++kt) {
        int pb = kt & 1;
        __syncthreads();
        if (kt < 31) {
            int k0 = (kt + 1) * 32;
            rx0 = *(const f16x8*)&gx0[k0];
            rx1 = *(const f16x8*)&gx1[k0];
            rw0 = *(const f16x8*)&gw0[k0];
            rw1 = *(const f16x8*)&gw1[k0];
        }
        const f16* la = smem + pb * 8192;
        const f16* lb = la + 4096;
        f16x8 af[4], bfr[4];
        #pragma unroll
        for (int i = 0; i < 4; i++) {
            int m = 64 * wr + 16 * i + lm;
            af[i] = *(const f16x8*)&la[m * 32 + (qd ^ (m & 3)) * 8];
            int n = 64 * wc + 16 * i + lm;
            bfr[i] = *(const f16x8*)&lb[n * 32 + (qd ^ (n & 3)) * 8];
        }
        __builtin_amdgcn_s_setprio(1);
        #pragma unroll
        for (int i = 0; i < 4; i++)
            #pragma unroll
            for (int j = 0; j < 4; j++)
                acc[i][j] = MFMA16(af[i], bfr[j], acc[i][j], 0, 0, 0);
        __builtin_amdgcn_s_setprio(0);
        __syncthreads();
        if (kt < 31) {
            f16* d = smem + (pb ^ 1) * 8192;
            *(f16x8*)&d[lw0] = rx0;
            *(f16x8*)&d[lw1] = rx1;
            *(f16x8*)&d[4096 + lw0] = rw0;
            *(f16x8*)&d[4096 + lw1] = rw1;
        }
    }

    #pragma unroll
    for (int j = 0; j < 4; j++) {
        int n = n0 + 64 * wc + 16 * j + lm;
        float bb = bo[n];
        #pragma unroll
        for (int i = 0; i < 4; i++) {
            int mbase = m0 + 64 * wr + 16 * i + 4 * qd;
            #pragma unroll
            for (int r = 0; r < 4; ++r)
                out[(long)(mbase + r) * 1024 + n] = acc[i][j][r] + bb;
        }
    }
}

// ---------------- launch ----------------------------------------------------
extern "C" void kernel_launch(void* const* d_in, const int* in_sizes, int n_in,
                              void* d_out, int out_size, void* d_ws, size_t ws_size,
                              hipStream_t stream)
{
    const float* embed = (const float*)d_in[0];
    const float* key   = (const float*)d_in[1];
    const int*   mask  = (const int*)d_in[2];
    const float* Wq = (const float*)d_in[3];
    const float* bq = (const float*)d_in[4];
    const float* Wk = (const float*)d_in[5];
    const float* bk = (const float*)d_in[6];
    const float* Wv = (const float*)d_in[7];
    const float* bv = (const float*)d_in[8];
    const float* Wo = (const float*)d_in[9];
    const float* bo = (const float*)d_in[10];

    char* ws = (char*)d_ws;
    f16* xe  = (f16*)(ws + 0);          // 8 MB
    f16* xk  = (f16*)(ws + 8388608);    // 8 MB
    f16* wqh = (f16*)(ws + 16777216);   // 2 MB
    f16* wkh = (f16*)(ws + 18874368);
    f16* wvh = (f16*)(ws + 20971520);
    f16* woh = (f16*)(ws + 23068672);
    f16* Qh  = (f16*)(ws + 25165824);   // 8 MB  [B][H][S][64]
    f16* Kh  = (f16*)(ws + 33554432);   // 8 MB
    f16* Vt  = (f16*)(ws + 41943040);   // 8 MB  [B][H][64][S]
    f16* Oh  = (f16*)(ws + 50331648);   // 8 MB  [B*S][1024]
    u64* mb  = (u64*)(ws + 58720256);   // 1 MB
    float* out = (float*)d_out;

    k_prep<<<7168, 256, 0, stream>>>(embed, key, Wq, Wk, Wv, Wo, mask,
                                     xe, xk, wqh, wkh, wvh, woh, mb);
    k_qkv<<<768, 256, 0, stream>>>(xe, xk, wqh, wkh, wvh, bq, bk, bv, Qh, Kh, Vt);
    k_attn<<<512, 512, 0, stream>>>(Qh, Kh, Vt, mb, Oh);
    k_proj<<<256, 256, 0, stream>>>(Oh, woh, bo, out);
}

// Round 10
// 260.902 us; speedup vs baseline: 1.0946x; 1.0151x over previous
//
#include <hip/hip_runtime.h>

// ---------------------------------------------------------------------------
// MultiheadAttention fwd, MI355X gfx950.
// B=2, S=2048, D=1024, H=16, DH=64.  Internal compute fp16 + fp32 MFMA acc.
// R13 (= R12 + gl16 staging in k_qkv ONLY — the clean A/B):
//   - k_qkv: reg-staging -> global_load_lds width=16 (m151: +35% at 128^2
//     tile), 1 barrier/iter (was 2), staging VGPRs freed. Swizzle algebra
//     identical to R12's (linear LDS dest, inverse-swizzled source).
//   - k_prep / k_attn / k_proj: byte-identical to R12 (passed, 264.8us;
//     attn stable 69-72us).
//   - If this round container-fails: gl16-GEMM gets its 3rd strike and is
//     permanently excluded; R12 (263-265us) stands as best.
// ---------------------------------------------------------------------------

typedef _Float16 f16;
typedef __attribute__((ext_vector_type(8))) _Float16 f16x8;
typedef __attribute__((ext_vector_type(4))) _Float16 f16x4;
typedef __attribute__((ext_vector_type(4))) float f32x4;
typedef unsigned long long u64;
typedef unsigned int u32;

#define MFMA16 __builtin_amdgcn_mfma_f32_16x16x32_f16
#define MFMA16K16 __builtin_amdgcn_mfma_f32_16x16x16f16

__device__ __forceinline__ void gl16(const f16* g, f16* l) {
    __builtin_amdgcn_global_load_lds(
        (const __attribute__((address_space(1))) void*)(const void*)g,
        (__attribute__((address_space(3))) void*)(void*)l,
        16, 0, 0);
}

// ---------------- kernel 1: convert + mask pack (merged, barrier-free) -----
__global__ __launch_bounds__(256) void k_prep(
    const float* __restrict__ embed, const float* __restrict__ key,
    const float* __restrict__ wq, const float* __restrict__ wk,
    const float* __restrict__ wv, const float* __restrict__ wo,
    const int* __restrict__ mask,
    f16* __restrict__ xe, f16* __restrict__ xk,
    f16* __restrict__ wqh, f16* __restrict__ wkh,
    f16* __restrict__ wvh, f16* __restrict__ woh,
    u64* __restrict__ bits)
{
    int bid = blockIdx.x;
    if (bid >= 6144) {
        // ---- mask packing: 1024 blocks, one mask row per wave ----
        int gw = ((bid - 6144) * 256 + (int)threadIdx.x) >> 6;   // 0..4095
        int lane = threadIdx.x & 63;
        const int* row = mask + (long)gw * 2048;
        u64* outp = bits + (long)gw * 32;
        #pragma unroll 4
        for (int c = 0; c < 32; ++c) {
            int v = row[c * 64 + lane];
            u64 b = __ballot(v != 0);
            if (lane == 0) outp[c] = b;
        }
        return;
    }
    // ---- fp32 -> f16 convert: one 8-float group per thread ----
    long g = (long)bid * 256 + threadIdx.x;
    const float* src; f16* dst; long off;
    if (g < 524288)       { src = embed; dst = xe; off = g; }
    else if (g < 1048576) { src = key;   dst = xk; off = g - 524288; }
    else {
        long t = g - 1048576; int wi = (int)(t >> 17); off = t & 131071;
        if (wi == 0)      { src = wq; dst = wqh; }
        else if (wi == 1) { src = wk; dst = wkh; }
        else if (wi == 2) { src = wv; dst = wvh; }
        else              { src = wo; dst = woh; }
    }
    const float4* s4 = (const float4*)src;
    float4 a = s4[off * 2], b = s4[off * 2 + 1];
    f16x8 o;
    o[0]=(f16)a.x; o[1]=(f16)a.y; o[2]=(f16)a.z; o[3]=(f16)a.w;
    o[4]=(f16)b.x; o[5]=(f16)b.y; o[6]=(f16)b.z; o[7]=(f16)b.w;
    *(f16x8*)(dst + off * 8) = o;
}

// ---------------- kernel 2: fused QKV GEMM (gl16 dbuf staging) -------------
// BK=32, 2x8KB LDS buffers, global_load_lds width=16: wave wid stages rows
// [wid*32, wid*32+32) of X and W; linear LDS dest, inverse-swizzled source.
// 1 barrier/iter (end barrier drains vmcnt). XCD-swizzled grid (768 = 8*96).
__global__ __launch_bounds__(256) void k_qkv(
    const f16* __restrict__ xe, const f16* __restrict__ xk,
    const f16* __restrict__ wqh, const f16* __restrict__ wkh, const f16* __restrict__ wvh,
    const float* __restrict__ bq, const float* __restrict__ bk, const float* __restrict__ bv,
    f16* __restrict__ Qh, f16* __restrict__ Kh, f16* __restrict__ Vt)
{
    int bid0 = blockIdx.x;
    int bid = (bid0 & 7) * 96 + (bid0 >> 3);      // XCD swizzle, 768 = 8*96
    int which = bid >> 8;
    int rr_ = bid & 255;
    int tm = rr_ >> 3, tn = rr_ & 7;
    const f16* X = (which == 0) ? xe : xk;
    const f16* W = (which == 0) ? wqh : (which == 1) ? wkh : wvh;
    const float* bias = (which == 0) ? bq : (which == 1) ? bk : bv;

    // 2 bufs x (la 4096 | lb 4096) = 16384 f16; Q/K bounce needs 17408 f16.
    __shared__ f16 smem[17408];

    int tid = threadIdx.x;
    int lane = tid & 63, wid = tid >> 6;
    int wr = wid >> 1, wc = wid & 1;
    int lm = lane & 15, qd = lane >> 4;

    f32x4 acc[4][4];
    #pragma unroll
    for (int i = 0; i < 4; i++)
        #pragma unroll
        for (int j = 0; j < 4; j++) acc[i][j] = (f32x4)0.0f;

    int m0 = tm * 128, n0 = tn * 128;

    // staging: one gl16 covers 16 rows x 32 f16 (4 lanes/row). Wave wid owns
    // rows [wid*32, wid*32+32) of both tiles; j=0/1 are the 16-row halves.
    // Global chunk cgl = (lane&3)^(row&3); LDS dest linear -> read-side
    // frag fetch at (qd^(m&3)) recovers global chunk qd.  [R6-audited]
    int rowl = lane >> 2;
    int cgl = (lane & 3) ^ (rowl & 3);
    const f16* gx = X + (long)(m0 + wid * 32 + rowl) * 1024 + cgl * 8;
    const f16* gw = W + (long)(n0 + wid * 32 + rowl) * 1024 + cgl * 8;

    #define QKV_STAGE(pb, kt)                                                  \
        {                                                                      \
            f16* d0 = smem + (pb) * 8192 + wid * 1024;                         \
            _Pragma("unroll")                                                  \
            for (int j = 0; j < 2; ++j) {                                      \
                gl16(gx + (kt) * 32 + j * 16384, d0 + j * 512);                \
                gl16(gw + (kt) * 32 + j * 16384, d0 + 4096 + j * 512);         \
            }                                                                  \
        }

    QKV_STAGE(0, 0);
    __syncthreads();                               // vmcnt drained, buf0 ready

    for (int kt = 0; kt < 32; ++kt) {
        int pb = kt & 1;
        if (kt < 31) QKV_STAGE(pb ^ 1, kt + 1);    // async into other buf
        const f16* la = smem + pb * 8192;
        const f16* lb = la + 4096;
        f16x8 af[4], bfr[4];
        #pragma unroll
        for (int i = 0; i < 4; i++) {
            int m = 64 * wr + 16 * i + lm;
            af[i] = *(const f16x8*)&la[m * 32 + (qd ^ (m & 3)) * 8];
            int n = 64 * wc + 16 * i + lm;
            bfr[i] = *(const f16x8*)&lb[n * 32 + (qd ^ (n & 3)) * 8];
        }
        __builtin_amdgcn_s_setprio(1);
        #pragma unroll
        for (int i = 0; i < 4; i++)
            #pragma unroll
            for (int j = 0; j < 4; j++)
                acc[i][j] = MFMA16(af[i], bfr[j], acc[i][j], 0, 0, 0);
        __builtin_amdgcn_s_setprio(0);
        __syncthreads();                           // drains vmcnt + lds reads
    }
    #undef QKV_STAGE

    if (which == 2) {
        // V: direct transposed store [B][H][64][S], b64 along s
        #pragma unroll
        for (int j = 0; j < 4; j++) {
            int n = n0 + 64 * wc + 16 * j + lm;
            float bb = bias[n];
            int h = n >> 6, d = n & 63;
            #pragma unroll
            for (int i = 0; i < 4; i++) {
                int mbase = m0 + 64 * wr + 16 * i + 4 * qd;
                f16x4 pk;
                #pragma unroll
                for (int r = 0; r < 4; ++r) pk[r] = (f16)(acc[i][j][r] + bb);
                int b = mbase >> 11, s = mbase & 2047;
                *(f16x4*)&Vt[(((long)(b * 16 + h)) * 64 + d) * 2048 + s] = pk;
            }
        }
    } else {
        // Q/K: LDS bounce -> coalesced b128 row stores.
        // Q pre-scaled by (1/32)*log2(e). Loop's final sync precedes this.
        f16* dst = (which == 0) ? Qh : Kh;
        float sc = (which == 0) ? 0.0450842252f : 1.0f;
        #pragma unroll
        for (int j = 0; j < 4; j++) {
            int col = 64 * wc + 16 * j + lm;
            float bb = bias[n0 + col];
            #pragma unroll
            for (int i = 0; i < 4; i++) {
                int row = 64 * wr + 16 * i + 4 * qd;
                #pragma unroll
                for (int r = 0; r < 4; ++r)
                    smem[(row + r) * 136 + col] = (f16)((acc[i][j][r] + bb) * sc);
            }
        }
        __syncthreads();
        #pragma unroll
        for (int t = 0; t < 8; ++t) {
            int ci = tid + t * 256;            // 0..2047
            int row = ci >> 4, cg = ci & 15;
            f16x8 v = *(const f16x8*)&smem[row * 136 + cg * 8];
            int m = m0 + row;
            int b = m >> 11, s = m & 2047;
            int h = (n0 >> 6) + (cg >> 3);
            int d0 = (cg & 7) * 8;
            *(f16x8*)&dst[(((long)(b * 16 + h)) * 2048 + s) * 64 + d0] = v;
        }
    }
}

// ---------------- kernel 3: flash attention (2-phase dbuf, kv-split) -------
// 512 threads = 8 waves. Wave wid: q-slice (wid&3)*32, kv-half wid>>2.
// 64-key sub-tiles, double-buffered: STAGE(next) issued before compute(cur),
// one barrier per iter. Partial (O,l) combine via LDS (no-max softmax).
__global__ __launch_bounds__(512, 4) void k_attn(
    const f16* __restrict__ Qh, const f16* __restrict__ Kh, const f16* __restrict__ Vt,
    const u64* __restrict__ mbits, f16* __restrict__ O)
{
    int bid0 = blockIdx.x;
    int bid = (bid0 & 7) * 64 + (bid0 >> 3);      // XCD swizzle, 512 = 8*64
    int qt = bid & 15;
    int h = (bid >> 4) & 15;
    int b = bid >> 8;
    int q0 = qt * 128;

    const f16* Qg = Qh + ((long)(b * 16 + h)) * 2048 * 64;
    const f16* Kg = Kh + ((long)(b * 16 + h)) * 2048 * 64;
    const f16* Vg = Vt + ((long)(b * 16 + h)) * 64 * 2048;

    // 64 KB: 2 bufs x 16384 f16; buf: K0(4096) K1(4096) V0(4096) V1(4096)
    __shared__ f16 smem[32768];

    int tid = threadIdx.x, lane = tid & 63, wid = tid >> 6;   // wid 0..7
    int lm = lane & 15, qd = lane >> 4;
    int qs = wid & 3;          // q-slice 0..3
    int hf = wid >> 2;         // kv half 0/1

    int qb = q0 + 32 * qs;
    const u64* Mrow0 = mbits + ((long)(b * 2048) + qb + lm) * 32;
    const u64* Mrow1 = Mrow0 + 16 * 32;

    // ---- staging: wave stages bi = wid>>1 (0,1=K half; 2,3=V half),
    //      sub-half sub = wid&1; 4 gl16/wave/iter (4KB each).
    int bi = wid >> 1, sub = wid & 1;
    int rowL = lane >> 3;
    int cgL = (lane & 7) ^ rowL;
    const f16* gsrc; long lstep, istep; int doff;
    if (bi < 2) {              // K half bi: [64 key][64 d] swizzled
        gsrc = Kg + ((long)(bi * 1024 + sub * 32 + rowL)) * 64 + cgL * 8;
        lstep = 512;           // +8 key rows
        istep = 4096;          // +64 key rows per iter
        doff = bi * 4096 + sub * 2048;
    } else {                   // V half vh: V^T [64 d][64 key] swizzled
        int vh = bi - 2;
        gsrc = Vg + ((long)(sub * 32 + rowL)) * 2048 + vh * 1024 + cgL * 8;
        lstep = 16384;         // +8 d rows
        istep = 64;            // +64 keys per iter
        doff = 8192 + vh * 4096 + sub * 2048;
    }

    #define ATTN_STAGE(pb, it)                                                 \
        {                                                                      \
            f16* d0 = smem + (pb) * 16384 + doff;                              \
            const f16* s0_ = gsrc + (it) * istep;                              \
            _Pragma("unroll")                                                  \
            for (int li = 0; li < 4; ++li)                                     \
                gl16(s0_ + li * lstep, d0 + li * 512);                         \
        }

    // Q fragments (MFMA B operand), per group per 32-d half
    f16x8 aq[2][2];
    #pragma unroll
    for (int g = 0; g < 2; ++g)
        #pragma unroll
        for (int ksi = 0; ksi < 2; ++ksi)
            aq[g][ksi] = *(const f16x8*)&Qg[(long)(qb + 16 * g + lm) * 64 + ksi * 32 + qd * 8];

    f32x4 oacc[2][4], lacc[2];
    #pragma unroll
    for (int g = 0; g < 2; ++g) {
        #pragma unroll
        for (int c = 0; c < 4; c++) oacc[g][c] = (f32x4)0.0f;
        lacc[g] = (f32x4)0.0f;
    }
    f16x4 vone4;
    #pragma unroll
    for (int j = 0; j < 4; j++) vone4[j] = (f16)1.0f;

    float negc2 = -__builtin_amdgcn_exp2f(-0.5f * (float)(h + 1)) * 0.0450842252f;

    int vgq = qd >> 1;
    int off4 = (qd & 1) * 4;

    ATTN_STAGE(0, 0);
    __syncthreads();

    for (int it = 0; it < 16; ++it) {
        int pb = it & 1;
        if (it < 15) ATTN_STAGE(pb ^ 1, it + 1);

        const f16* ksH = smem + pb * 16384 + hf * 4096;
        const f16* vsH = smem + pb * 16384 + 8192 + hf * 4096;

        u64 wa = Mrow0[hf * 16 + it];
        u64 wb = Mrow1[hf * 16 + it];
        float qmk0 = (float)(qb + lm - hf * 1024 - it * 64 - 4 * qd);
        float qmk1 = qmk0 + 16.0f;

        #pragma unroll
        for (int c = 0; c < 4; ++c) {
            // S^T = K * Q^T for this 16-key chunk, both q-groups
            int kr = 16 * c + lm;
            f32x4 s0 = (f32x4)0.0f, s1 = (f32x4)0.0f;
            __builtin_amdgcn_s_setprio(1);
            #pragma unroll
            for (int ksi = 0; ksi < 2; ++ksi) {
                int gg = (ksi * 4 + qd) ^ (kr & 7);
                f16x8 ak = *(const f16x8*)&ksH[kr * 64 + gg * 8];
                s0 = MFMA16(ak, aq[0][ksi], s0, 0, 0, 0);
                s1 = MFMA16(ak, aq[1][ksi], s1, 0, 0, 0);
            }
            __builtin_amdgcn_s_setprio(0);
            // softmax (4 keys per lane at fixed q)
            u32 niba = (u32)(wa >> (16 * c + 4 * qd)) & 15u;
            u32 nibb = (u32)(wb >> (16 * c + 4 * qd)) & 15u;
            float qc0 = qmk0 - 16.0f * (float)c;
            float qc1 = qmk1 - 16.0f * (float)c;
            f16x4 pk0, pk1;
            #pragma unroll
            for (int r = 0; r < 4; ++r) {
                float u0 = fmaf(fabsf(qc0 - (float)r), negc2, s0[r]);
                u0 = ((niba >> r) & 1u) ? u0 : -1e30f;
                pk0[r] = (f16)__builtin_amdgcn_exp2f(u0);
                float u1 = fmaf(fabsf(qc1 - (float)r), negc2, s1[r]);
                u1 = ((nibb >> r) & 1u) ? u1 : -1e30f;
                pk1[r] = (f16)__builtin_amdgcn_exp2f(u1);
            }
            // O += P V : K=16 MFMA, A=pk (regs), B=V^T b64 from LDS
            int vgc = 2 * c + vgq;
            __builtin_amdgcn_s_setprio(1);
            #pragma unroll
            for (int cc = 0; cc < 4; ++cc) {
                int d = 16 * cc + lm;
                f16x4 vb = *(const f16x4*)&vsH[d * 64 + (vgc ^ (d & 7)) * 8 + off4];
                oacc[0][cc] = MFMA16K16(pk0, vb, oacc[0][cc], 0, 0, 0);
                oacc[1][cc] = MFMA16K16(pk1, vb, oacc[1][cc], 0, 0, 0);
            }
            lacc[0] = MFMA16K16(pk0, vone4, lacc[0], 0, 0, 0);
            lacc[1] = MFMA16K16(pk1, vone4, lacc[1], 0, 0, 0);
            __builtin_amdgcn_s_setprio(0);
        }
        __syncthreads();
    }
    #undef ATTN_STAGE

    // ---- combine epilogue: half 1 -> LDS, half 0 adds, normalize, bounce ---
    float* cO = (float*)smem;                     // [4][32][64] f32, 32 KB
    float* lL = (float*)(smem + 16384);           // [4][32] f32
    f16*  fO  = smem + 16640;                     // [4][32][64] f16, 16 KB

    if (hf == 1) {
        #pragma unroll
        for (int g = 0; g < 2; ++g) {
            #pragma unroll
            for (int cc = 0; cc < 4; ++cc)
                #pragma unroll
                for (int r = 0; r < 4; ++r)
                    cO[(qs * 32 + 16 * g + 4 * qd + r) * 64 + 16 * cc + lm] = oacc[g][cc][r];
            if (lm == 0) {
                #pragma unroll
                for (int r = 0; r < 4; ++r)
                    lL[qs * 32 + 16 * g + 4 * qd + r] = lacc[g][r];
            }
        }
    }
    __syncthreads();
    if (hf == 0) {
        #pragma unroll
        for (int g = 0; g < 2; ++g) {
            float linv[4];
            #pragma unroll
            for (int r = 0; r < 4; ++r)
                linv[r] = 1.0f / fmaxf(lacc[g][r] + lL[qs * 32 + 16 * g + 4 * qd + r], 1e-30f);
            #pragma unroll
            for (int cc = 0; cc < 4; ++cc)
                #pragma unroll
                for (int r = 0; r < 4; ++r) {
                    int idx = (qs * 32 + 16 * g + 4 * qd + r) * 64 + 16 * cc + lm;
                    fO[idx] = (f16)((oacc[g][cc][r] + cO[idx]) * linv[r]);
                }
        }
    }
    __syncthreads();
    // coalesced O store: 1024 chunks of 8 f16
    #pragma unroll
    for (int t = 0; t < 2; ++t) {
        int ci = tid + t * 512;                   // 0..1023
        int q = ci >> 3, dc = ci & 7;
        f16x8 v = *(const f16x8*)&fO[q * 64 + dc * 8];
        *(f16x8*)&O[((long)(b * 2048 + q0 + q)) * 1024 + h * 64 + dc * 8] = v;
    }
}

// ---------------- kernel 4: output projection (T14 dbuf reg-staged) --------
__global__ __launch_bounds__(256) void k_proj(
    const f16* __restrict__ Oh, const f16* __restrict__ woh,
    const float* __restrict__ bo, float* __restrict__ out)
{
    int bid0 = blockIdx.x;
    int bid = (bid0 & 7) * 32 + (bid0 >> 3);      // XCD swizzle, 256 = 8*32
    int tm = bid >> 3, tn = bid & 7;

    __shared__ f16 smem[16384];   // 2 bufs x (la 4096 | lb 4096)

    int tid = threadIdx.x;
    int lane = tid & 63, wid = tid >> 6;
    int wr = wid >> 1, wc = wid & 1;
    int lm = lane & 15, qd = lane >> 4;

    f32x4 acc[4][4];
    #pragma unroll
    for (int i = 0; i < 4; i++)
        #pragma unroll
        for (int j = 0; j < 4; j++) acc[i][j] = (f32x4)0.0f;

    int m0 = tm * 128, n0 = tn * 128;

    int row0 = tid >> 2, cg0 = tid & 3;
    int row1 = (tid + 256) >> 2, cg1 = (tid + 256) & 3;
    int lw0 = row0 * 32 + (cg0 ^ (row0 & 3)) * 8;
    int lw1 = row1 * 32 + (cg1 ^ (row1 & 3)) * 8;
    const f16* gx0 = Oh  + (long)(m0 + row0) * 1024 + cg0 * 8;
    const f16* gx1 = Oh  + (long)(m0 + row1) * 1024 + cg1 * 8;
    const f16* gw0 = woh + (long)(n0 + row0) * 1024 + cg0 * 8;
    const f16* gw1 = woh + (long)(n0 + row1) * 1024 + cg1 * 8;

    f16x8 rx0, rx1, rw0, rw1;
    rx0 = *(const f16x8*)&gx0[0];
    rx1 = *(const f16x8*)&gx1[0];
    rw0 = *(const f16x8*)&gw0[0];
    rw1 = *(const f16x8*)&gw1[0];
    *(f16x8*)&smem[lw0] = rx0;
    *(f16x8*)&smem[lw1] = rx1;
    *(f16x8*)&smem[4096 + lw0] = rw0;
    *(f16x8*)&smem[4096 + lw1] = rw1;

    for (int kt = 0; kt < 32; ++kt) {
        int pb = kt & 1;
        __syncthreads();
        if (kt < 31) {
            int k0 = (kt + 1) * 32;
            rx0 = *(const f16x8*)&gx0[k0];
            rx1 = *(const f16x8*)&gx1[k0];
            rw0 = *(const f16x8*)&gw0[k0];
            rw1 = *(const f16x8*)&gw1[k0];
        }
        const f16* la = smem + pb * 8192;
        const f16* lb = la + 4096;
        f16x8 af[4], bfr[4];
        #pragma unroll
        for (int i = 0; i < 4; i++) {
            int m = 64 * wr + 16 * i + lm;
            af[i] = *(const f16x8*)&la[m * 32 + (qd ^ (m & 3)) * 8];
            int n = 64 * wc + 16 * i + lm;
            bfr[i] = *(const f16x8*)&lb[n * 32 + (qd ^ (n & 3)) * 8];
        }
        __builtin_amdgcn_s_setprio(1);
        #pragma unroll
        for (int i = 0; i < 4; i++)
            #pragma unroll
            for (int j = 0; j < 4; j++)
                acc[i][j] = MFMA16(af[i], bfr[j], acc[i][j], 0, 0, 0);
        __builtin_amdgcn_s_setprio(0);
        __syncthreads();
        if (kt < 31) {
            f16* d = smem + (pb ^ 1) * 8192;
            *(f16x8*)&d[lw0] = rx0;
            *(f16x8*)&d[lw1] = rx1;
            *(f16x8*)&d[4096 + lw0] = rw0;
            *(f16x8*)&d[4096 + lw1] = rw1;
        }
    }

    #pragma unroll
    for (int j = 0; j < 4; j++) {
        int n = n0 + 64 * wc + 16 * j + lm;
        float bb = bo[n];
        #pragma unroll
        for (int i = 0; i < 4; i++) {
            int mbase = m0 + 64 * wr + 16 * i + 4 * qd;
            #pragma unroll
            for (int r = 0; r < 4; ++r)
                out[(long)(mbase + r) * 1024 + n] = acc[i][j][r] + bb;
        }
    }
}

// ---------------- launch ----------------------------------------------------
extern "C" void kernel_launch(void* const* d_in, const int* in_sizes, int n_in,
                              void* d_out, int out_size, void* d_ws, size_t ws_size,
                              hipStream_t stream)
{
    const float* embed = (const float*)d_in[0];
    const float* key   = (const float*)d_in[1];
    const int*   mask  = (const int*)d_in[2];
    const float* Wq = (const float*)d_in[3];
    const float* bq = (const float*)d_in[4];
    const float* Wk = (const float*)d_in[5];
    const float* bk = (const float*)d_in[6];
    const float* Wv = (const float*)d_in[7];
    const float* bv = (const float*)d_in[8];
    const float* Wo = (const float*)d_in[9];
    const float* bo = (const float*)d_in[10];

    char* ws = (char*)d_ws;
    f16* xe  = (f16*)(ws + 0);          // 8 MB
    f16* xk  = (f16*)(ws + 8388608);    // 8 MB
    f16* wqh = (f16*)(ws + 16777216);   // 2 MB
    f16* wkh = (f16*)(ws + 18874368);
    f16* wvh = (f16*)(ws + 20971520);
    f16* woh = (f16*)(ws + 23068672);
    f16* Qh  = (f16*)(ws + 25165824);   // 8 MB  [B][H][S][64]
    f16* Kh  = (f16*)(ws + 33554432);   // 8 MB
    f16* Vt  = (f16*)(ws + 41943040);   // 8 MB  [B][H][64][S]
    f16* Oh  = (f16*)(ws + 50331648);   // 8 MB  [B*S][1024]
    u64* mb  = (u64*)(ws + 58720256);   // 1 MB
    float* out = (float*)d_out;

    k_prep<<<7168, 256, 0, stream>>>(embed, key, Wq, Wk, Wv, Wo, mask,
                                     xe, xk, wqh, wkh, wvh, woh, mb);
    k_qkv<<<768, 256, 0, stream>>>(xe, xk, wqh, wkh, wvh, bq, bk, bv, Qh, Kh, Vt);
    k_attn<<<512, 512, 0, stream>>>(Qh, Kh, Vt, mb, Oh);
    k_proj<<<256, 256, 0, stream>>>(Oh, woh, bo, out);
}